// Round 4
// baseline (279.758 us; speedup 1.0000x reference)
//
#include <hip/hip_runtime.h>

#define MARGIN_NEG 0.4f
#define MARGIN_POS 0.01f

// Problem constants: B=64, C=3, H=W=256 -> N = 12,582,912 elems; z: 64 x 16384
#define N_ELEM   12582912
#define N4       (N_ELEM / 4)          // 3,145,728 float4 per tensor
#define BATCH    64
#define DIMZ     16384
#define ROW4     (DIMZ / 4)            // 4096 float4 per z-row

// Native clang vector type: required by __builtin_nontemporal_load.
typedef float vf4 __attribute__((ext_vector_type(4)));

// R4: contrastive moves to an 8x8 register tile (64 accumulators). 16 loads
// produce 64 pair-partials (vs 8 loads -> 16 before): z logical request
// traffic halves, 134 -> 67 MB. Total L1-level request volume drops ~20%
// while MSE bytes are untouched -- decisive test of the shared
// outstanding-request-budget theory (R1/R2 exonerated policy+geometry;
// FETCH_SIZE is harness-structural per R1/R3).
// CB = 64 tiles x 4 k-chunks = 256 blocks, FIRST in grid (R3 win).
// __launch_bounds__(256,4) caps VGPR at 128 so the MSE branch (76 VGPR)
// and its occupancy are unchanged.
#define MSE_BLKS  1536
#define F4_PER_STREAM_BLK 2048         // N4 / MSE_BLKS
#define CB        256                  // contrastive blocks (FIRST in grid)

// ws layout (floats), all plain stores, every slot written exactly once:
//   [kc*4096 + m*64 + n], kc in 0..3 : contrastive partial d sums   (16384)
//   [16384 + mseBlock]               : per-block MSE partials       (1536)
#define MSE_OFF  16384

__global__ __launch_bounds__(256, 4) void fused_pass1(
        const float* __restrict__ o1, const float* __restrict__ i1,
        const float* __restrict__ o2, const float* __restrict__ i2,
        const float* __restrict__ z1, const float* __restrict__ z2,
        float* __restrict__ ws) {
    const int b = blockIdx.x;
    const int t = threadIdx.x;
    const int lane = t & 63, wid = t >> 6;

    if (b >= CB) {
        // ------- MSE: single-batch nt streaming, unchanged from R2/R3 -------
        const int mb = b - CB;
        const vf4* A1 = (const vf4*)o1;
        const vf4* B1 = (const vf4*)i1;
        const vf4* A2 = (const vf4*)o2;
        const vf4* B2 = (const vf4*)i2;
        const int base = mb * F4_PER_STREAM_BLK + t;  // stream-local f4 index

        vf4 a1[8], a2[8], b1[8], b2[8];
        #pragma unroll
        for (int j = 0; j < 8; j++) a1[j] = __builtin_nontemporal_load(&A1[base + j * 256]);
        #pragma unroll
        for (int j = 0; j < 8; j++) a2[j] = __builtin_nontemporal_load(&A2[base + j * 256]);
        #pragma unroll
        for (int j = 0; j < 8; j++) b1[j] = __builtin_nontemporal_load(&B1[base + j * 256]);
        #pragma unroll
        for (int j = 0; j < 8; j++) b2[j] = __builtin_nontemporal_load(&B2[base + j * 256]);

        float acc0 = 0.f, acc1 = 0.f, acc2 = 0.f, acc3 = 0.f;
        #pragma unroll
        for (int j = 0; j < 8; j++) {
            vf4 d1 = a1[j] - b1[j];
            vf4 d2 = a2[j] - b2[j];
            acc0 += d1.x * d1.x + d1.y * d1.y;
            acc1 += d1.z * d1.z + d1.w * d1.w;
            acc2 += d2.x * d2.x + d2.y * d2.y;
            acc3 += d2.z * d2.z + d2.w * d2.w;
        }
        float v = (acc0 + acc1) + (acc2 + acc3);
        #pragma unroll
        for (int off = 32; off > 0; off >>= 1) v += __shfl_down(v, off, 64);
        __shared__ float ws4[4];
        if (lane == 0) ws4[wid] = v;
        __syncthreads();
        if (t == 0) ws[MSE_OFF + mb] = ws4[0] + ws4[1] + ws4[2] + ws4[3];
    } else {
        // ---- contrastive: 8x8 register tile over (m,n), k-split x4 ----
        const int kc   = b & 3;             // k-chunk: 1024 float4 = 4096 floats
        const int tile = b >> 2;            // 0..63
        const int m0 = (tile >> 3) * 8;
        const int n0 = (tile & 7) * 8;
        const vf4* z1v = (const vf4*)z1;
        const vf4* z2v = (const vf4*)z2;

        float acc[64];
        #pragma unroll
        for (int p = 0; p < 64; p++) acc[p] = 0.f;

        const int cbase = kc * 1024 + t;
        #pragma unroll
        for (int it = 0; it < 4; it++) {
            const int c = cbase + it * 256;
            vf4 a[8];
            #pragma unroll
            for (int i = 0; i < 8; i++)
                a[i] = __builtin_nontemporal_load(&z1v[(m0 + i) * ROW4 + c]);
            #pragma unroll
            for (int j = 0; j < 8; j++) {
                vf4 bz = __builtin_nontemporal_load(&z2v[(n0 + j) * ROW4 + c]);
                #pragma unroll
                for (int i = 0; i < 8; i++) {
                    float dx = a[i].x - bz.x, dy = a[i].y - bz.y;
                    float dz = a[i].z - bz.z, dw = a[i].w - bz.w;
                    acc[i * 8 + j] += dx * dx + dy * dy + dz * dz + dw * dw;
                }
            }
        }

        // Reduce each of the 64 pair-partials across the wave, then across waves.
        __shared__ float wsum[4][64];
        #pragma unroll
        for (int p = 0; p < 64; p++) {
            float v = acc[p];
            #pragma unroll
            for (int off = 32; off > 0; off >>= 1) v += __shfl_down(v, off, 64);
            if (lane == 0) wsum[wid][p] = v;
        }
        __syncthreads();
        if (t < 64) {
            float s = wsum[0][t] + wsum[1][t] + wsum[2][t] + wsum[3][t];
            int m = m0 + (t >> 3), n = n0 + (t & 7);
            ws[kc * 4096 + m * 64 + n] = s;   // plain store, unique slot
        }
    }
}

// Reduce partials + margins + finalize: one block of 256 threads.
__global__ __launch_bounds__(256) void fused_pass2(const float* __restrict__ ws,
                                                   float* __restrict__ out) {
    const int t = threadIdx.x;
    const int lane = t & 63, wid = t >> 6;

    float msum = 0.f;
    #pragma unroll
    for (int s = 0; s < 6; s++) msum += ws[MSE_OFF + t + s * 256];  // 1536 partials

    float p = 0.f, q = 0.f;
    #pragma unroll
    for (int s = 0; s < 16; s++) {
        int idx = t + s * 256;                                       // 4096 pairs
        float d = (ws[idx] + ws[4096 + idx] + ws[8192 + idx] + ws[12288 + idx])
                  * (1.0f / (float)DIMZ);
        int m = idx >> 6, n = idx & 63;
        if (m == n) { if (d > MARGIN_POS) p += d - MARGIN_POS; }
        else        { if (d < MARGIN_NEG) q += MARGIN_NEG - d; }
    }

    #pragma unroll
    for (int off = 32; off > 0; off >>= 1) {
        msum += __shfl_down(msum, off, 64);
        p    += __shfl_down(p,    off, 64);
        q    += __shfl_down(q,    off, 64);
    }
    __shared__ float sm[4], sp[4], sq[4];
    if (lane == 0) { sm[wid] = msum; sp[wid] = p; sq[wid] = q; }
    __syncthreads();
    if (t == 0) {
        float M = sm[0] + sm[1] + sm[2] + sm[3];
        float P = sp[0] + sp[1] + sp[2] + sp[3];
        float Q = sq[0] + sq[1] + sq[2] + sq[3];
        out[0] = M * (1.0f / (float)N_ELEM)
               + 1.5f * (P / (float)BATCH)
               + 0.5f * (Q / (float)(BATCH * (BATCH - 1)));
    }
}

extern "C" void kernel_launch(void* const* d_in, const int* in_sizes, int n_in,
                              void* d_out, int out_size, void* d_ws, size_t ws_size,
                              hipStream_t stream) {
    const float* outputs1 = (const float*)d_in[0];
    const float* z1       = (const float*)d_in[1];
    const float* outputs2 = (const float*)d_in[2];
    const float* z2       = (const float*)d_in[3];
    const float* input1   = (const float*)d_in[4];
    const float* input2   = (const float*)d_in[5];
    float* out = (float*)d_out;
    float* ws  = (float*)d_ws;

    fused_pass1<<<MSE_BLKS + CB, 256, 0, stream>>>(outputs1, input1, outputs2, input2,
                                                   z1, z2, ws);
    fused_pass2<<<1, 256, 0, stream>>>(ws, out);
}

// Round 6
// 212.580 us; speedup vs baseline: 1.3160x; 1.3160x over previous
//
#include <hip/hip_runtime.h>

#define MARGIN_NEG 0.4f
#define MARGIN_POS 0.01f

// Problem constants: B=64, C=3, H=W=256 -> N = 12,582,912 elems; z: 64 x 16384
#define N_ELEM   12582912
#define N4       (N_ELEM / 4)          // 3,145,728 float4 per tensor
#define BATCH    64
#define DIMZ     16384
#define ROW4     (DIMZ / 4)            // 4096 float4 per z-row

// Native clang vector type: required by __builtin_nontemporal_load.
typedef float vf4 __attribute__((ext_vector_type(4)));

// R6 == R5 resubmitted (R5 never ran: container infra failure, no counters).
// R5 rationale: R4's 8x8-tile experiment RE-RUN WITHOUT THE VGPR CAP. R4's
// __launch_bounds__(256,4) clamped VGPRs to 128 < the ~130 the 8x8 tile
// needs -> massive scratch spill (WRITE_SIZE 0.18->48 MB, pass1 130 us).
// The request-volume theory was never tested. Plain __launch_bounds__(256)
// lets the tile live in registers (~130 VGPR still allows 4 waves/SIMD,
// above the ~7 waves/CU actually resident, so MSE occupancy unaffected).
// Everything else identical to R3 (198.6 us).
#define MSE_BLKS  1536
#define F4_PER_STREAM_BLK 2048         // N4 / MSE_BLKS
#define CB        256                  // contrastive blocks (FIRST in grid)

// ws layout (floats), all plain stores, every slot written exactly once:
//   [kc*4096 + m*64 + n], kc in 0..3 : contrastive partial d sums   (16384)
//   [16384 + mseBlock]               : per-block MSE partials       (1536)
#define MSE_OFF  16384

__global__ __launch_bounds__(256) void fused_pass1(
        const float* __restrict__ o1, const float* __restrict__ i1,
        const float* __restrict__ o2, const float* __restrict__ i2,
        const float* __restrict__ z1, const float* __restrict__ z2,
        float* __restrict__ ws) {
    const int b = blockIdx.x;
    const int t = threadIdx.x;
    const int lane = t & 63, wid = t >> 6;

    if (b >= CB) {
        // ------- MSE: single-batch nt streaming, unchanged from R2/R3 -------
        const int mb = b - CB;
        const vf4* A1 = (const vf4*)o1;
        const vf4* B1 = (const vf4*)i1;
        const vf4* A2 = (const vf4*)o2;
        const vf4* B2 = (const vf4*)i2;
        const int base = mb * F4_PER_STREAM_BLK + t;  // stream-local f4 index

        vf4 a1[8], a2[8], b1[8], b2[8];
        #pragma unroll
        for (int j = 0; j < 8; j++) a1[j] = __builtin_nontemporal_load(&A1[base + j * 256]);
        #pragma unroll
        for (int j = 0; j < 8; j++) a2[j] = __builtin_nontemporal_load(&A2[base + j * 256]);
        #pragma unroll
        for (int j = 0; j < 8; j++) b1[j] = __builtin_nontemporal_load(&B1[base + j * 256]);
        #pragma unroll
        for (int j = 0; j < 8; j++) b2[j] = __builtin_nontemporal_load(&B2[base + j * 256]);

        float acc0 = 0.f, acc1 = 0.f, acc2 = 0.f, acc3 = 0.f;
        #pragma unroll
        for (int j = 0; j < 8; j++) {
            vf4 d1 = a1[j] - b1[j];
            vf4 d2 = a2[j] - b2[j];
            acc0 += d1.x * d1.x + d1.y * d1.y;
            acc1 += d1.z * d1.z + d1.w * d1.w;
            acc2 += d2.x * d2.x + d2.y * d2.y;
            acc3 += d2.z * d2.z + d2.w * d2.w;
        }
        float v = (acc0 + acc1) + (acc2 + acc3);
        #pragma unroll
        for (int off = 32; off > 0; off >>= 1) v += __shfl_down(v, off, 64);
        __shared__ float ws4[4];
        if (lane == 0) ws4[wid] = v;
        __syncthreads();
        if (t == 0) ws[MSE_OFF + mb] = ws4[0] + ws4[1] + ws4[2] + ws4[3];
    } else {
        // ---- contrastive: 8x8 register tile over (m,n), k-split x4 ----
        const int kc   = b & 3;             // k-chunk: 1024 float4 = 4096 floats
        const int tile = b >> 2;            // 0..63
        const int m0 = (tile >> 3) * 8;
        const int n0 = (tile & 7) * 8;
        const vf4* z1v = (const vf4*)z1;
        const vf4* z2v = (const vf4*)z2;

        float acc[64];
        #pragma unroll
        for (int p = 0; p < 64; p++) acc[p] = 0.f;

        const int cbase = kc * 1024 + t;
        #pragma unroll
        for (int it = 0; it < 4; it++) {
            const int c = cbase + it * 256;
            vf4 a[8];
            #pragma unroll
            for (int i = 0; i < 8; i++)
                a[i] = __builtin_nontemporal_load(&z1v[(m0 + i) * ROW4 + c]);
            #pragma unroll
            for (int j = 0; j < 8; j++) {
                vf4 bz = __builtin_nontemporal_load(&z2v[(n0 + j) * ROW4 + c]);
                #pragma unroll
                for (int i = 0; i < 8; i++) {
                    float dx = a[i].x - bz.x, dy = a[i].y - bz.y;
                    float dz = a[i].z - bz.z, dw = a[i].w - bz.w;
                    acc[i * 8 + j] += dx * dx + dy * dy + dz * dz + dw * dw;
                }
            }
        }

        // Reduce each of the 64 pair-partials across the wave, then across waves.
        __shared__ float wsum[4][64];
        #pragma unroll
        for (int p = 0; p < 64; p++) {
            float v = acc[p];
            #pragma unroll
            for (int off = 32; off > 0; off >>= 1) v += __shfl_down(v, off, 64);
            if (lane == 0) wsum[wid][p] = v;
        }
        __syncthreads();
        if (t < 64) {
            float s = wsum[0][t] + wsum[1][t] + wsum[2][t] + wsum[3][t];
            int m = m0 + (t >> 3), n = n0 + (t & 7);
            ws[kc * 4096 + m * 64 + n] = s;   // plain store, unique slot
        }
    }
}

// Reduce partials + margins + finalize: one block of 256 threads.
__global__ __launch_bounds__(256) void fused_pass2(const float* __restrict__ ws,
                                                   float* __restrict__ out) {
    const int t = threadIdx.x;
    const int lane = t & 63, wid = t >> 6;

    float msum = 0.f;
    #pragma unroll
    for (int s = 0; s < 6; s++) msum += ws[MSE_OFF + t + s * 256];  // 1536 partials

    float p = 0.f, q = 0.f;
    #pragma unroll
    for (int s = 0; s < 16; s++) {
        int idx = t + s * 256;                                       // 4096 pairs
        float d = (ws[idx] + ws[4096 + idx] + ws[8192 + idx] + ws[12288 + idx])
                  * (1.0f / (float)DIMZ);
        int m = idx >> 6, n = idx & 63;
        if (m == n) { if (d > MARGIN_POS) p += d - MARGIN_POS; }
        else        { if (d < MARGIN_NEG) q += MARGIN_NEG - d; }
    }

    #pragma unroll
    for (int off = 32; off > 0; off >>= 1) {
        msum += __shfl_down(msum, off, 64);
        p    += __shfl_down(p,    off, 64);
        q    += __shfl_down(q,    off, 64);
    }
    __shared__ float sm[4], sp[4], sq[4];
    if (lane == 0) { sm[wid] = msum; sp[wid] = p; sq[wid] = q; }
    __syncthreads();
    if (t == 0) {
        float M = sm[0] + sm[1] + sm[2] + sm[3];
        float P = sp[0] + sp[1] + sp[2] + sp[3];
        float Q = sq[0] + sq[1] + sq[2] + sq[3];
        out[0] = M * (1.0f / (float)N_ELEM)
               + 1.5f * (P / (float)BATCH)
               + 0.5f * (Q / (float)(BATCH * (BATCH - 1)));
    }
}

extern "C" void kernel_launch(void* const* d_in, const int* in_sizes, int n_in,
                              void* d_out, int out_size, void* d_ws, size_t ws_size,
                              hipStream_t stream) {
    const float* outputs1 = (const float*)d_in[0];
    const float* z1       = (const float*)d_in[1];
    const float* outputs2 = (const float*)d_in[2];
    const float* z2       = (const float*)d_in[3];
    const float* input1   = (const float*)d_in[4];
    const float* input2   = (const float*)d_in[5];
    float* out = (float*)d_out;
    float* ws  = (float*)d_ws;

    fused_pass1<<<MSE_BLKS + CB, 256, 0, stream>>>(outputs1, input1, outputs2, input2,
                                                   z1, z2, ws);
    fused_pass2<<<1, 256, 0, stream>>>(ws, out);
}

// Round 7
// 199.799 us; speedup vs baseline: 1.4002x; 1.0640x over previous
//
#include <hip/hip_runtime.h>

#define MARGIN_NEG 0.4f
#define MARGIN_POS 0.01f

// Problem constants: B=64, C=3, H=W=256 -> N = 12,582,912 elems; z: 64 x 16384
#define N_ELEM   12582912
#define N4       (N_ELEM / 4)          // 3,145,728 float4 per tensor
#define BATCH    64
#define DIMZ     16384
#define ROW4     (DIMZ / 4)            // 4096 float4 per z-row

// Native clang vector type: required by __builtin_nontemporal_load.
typedef float vf4 __attribute__((ext_vector_type(4)));

// R7: revert to R3 structure (4x4 tile, 76 VGPR -- best measured: 45 us pass1).
// R6 taught: 8x8 tile's VGPR=140 throttled MSE occupancy (22%->9.8%) and lost
// more than halved z-traffic gained; request ISSUE rate is provably not the
// limit. Last live lever: z L2 residency. Contrastive tiles are remapped so
// XCD r (= blockIdx%8 under round-robin dispatch) owns a 4x8 super-region of
// the 16x16 tile grid -> per-XCD z footprint 1 MB z1 + 2 MB z2 = 3 MB < 4 MB
// L2 (was ~8 MB thrashing). z loads are PLAIN (nt = evict-first in L2, wrong
// for data we want L2-resident); MSE streams stay nt.
#define MSE_BLKS  1536
#define F4_PER_STREAM_BLK 2048         // N4 / MSE_BLKS
#define CB        1024                 // contrastive blocks (FIRST in grid)

// ws layout (floats), all plain stores, every slot written exactly once:
//   [kc*4096 + m*64 + n], kc in 0..3 : contrastive partial d sums   (16384)
//   [16384 + mseBlock]               : per-block MSE partials       (1536)
#define MSE_OFF  16384

__global__ __launch_bounds__(256) void fused_pass1(
        const float* __restrict__ o1, const float* __restrict__ i1,
        const float* __restrict__ o2, const float* __restrict__ i2,
        const float* __restrict__ z1, const float* __restrict__ z2,
        float* __restrict__ ws) {
    const int b = blockIdx.x;
    const int t = threadIdx.x;
    const int lane = t & 63, wid = t >> 6;

    if (b >= CB) {
        // ------- MSE: single-batch nt streaming, unchanged from R2/R3 -------
        const int mb = b - CB;
        const vf4* A1 = (const vf4*)o1;
        const vf4* B1 = (const vf4*)i1;
        const vf4* A2 = (const vf4*)o2;
        const vf4* B2 = (const vf4*)i2;
        const int base = mb * F4_PER_STREAM_BLK + t;  // stream-local f4 index

        vf4 a1[8], a2[8], b1[8], b2[8];
        #pragma unroll
        for (int j = 0; j < 8; j++) a1[j] = __builtin_nontemporal_load(&A1[base + j * 256]);
        #pragma unroll
        for (int j = 0; j < 8; j++) a2[j] = __builtin_nontemporal_load(&A2[base + j * 256]);
        #pragma unroll
        for (int j = 0; j < 8; j++) b1[j] = __builtin_nontemporal_load(&B1[base + j * 256]);
        #pragma unroll
        for (int j = 0; j < 8; j++) b2[j] = __builtin_nontemporal_load(&B2[base + j * 256]);

        float acc0 = 0.f, acc1 = 0.f, acc2 = 0.f, acc3 = 0.f;
        #pragma unroll
        for (int j = 0; j < 8; j++) {
            vf4 d1 = a1[j] - b1[j];
            vf4 d2 = a2[j] - b2[j];
            acc0 += d1.x * d1.x + d1.y * d1.y;
            acc1 += d1.z * d1.z + d1.w * d1.w;
            acc2 += d2.x * d2.x + d2.y * d2.y;
            acc3 += d2.z * d2.z + d2.w * d2.w;
        }
        float v = (acc0 + acc1) + (acc2 + acc3);
        #pragma unroll
        for (int off = 32; off > 0; off >>= 1) v += __shfl_down(v, off, 64);
        __shared__ float ws4[4];
        if (lane == 0) ws4[wid] = v;
        __syncthreads();
        if (t == 0) ws[MSE_OFF + mb] = ws4[0] + ws4[1] + ws4[2] + ws4[3];
    } else {
        // ---- contrastive: 4x4 register tile, XCD-region swizzled ----
        // cb -> (region r = cb&7, slot): region r owns a 4x8 block of the
        // 16x16 tile grid. Under blockIdx%8 XCD round-robin, all blocks of a
        // region land on one XCD; its z working set (16 z1 rows + 32 z2 rows
        // = 3 MB) fits the 4 MB per-XCD L2. Bijection:
        //   mb = (r>>1)*4 + (tin>>3), nb = (r&1)*8 + (tin&7), tin = slot>>2,
        //   kc = slot&3.
        const int r    = b & 7;
        const int slot = b >> 3;            // 0..127
        const int kc   = slot & 3;          // k-chunk: 1024 float4
        const int tin  = slot >> 2;         // 0..31 tile-in-region
        const int m0 = ((r >> 1) * 4 + (tin >> 3)) * 4;
        const int n0 = ((r & 1) * 8 + (tin & 7)) * 4;
        const float4* z1v = (const float4*)z1;
        const float4* z2v = (const float4*)z2;

        float acc[16];
        #pragma unroll
        for (int p = 0; p < 16; p++) acc[p] = 0.f;

        const int cbase = kc * 1024 + t;
        #pragma unroll
        for (int it = 0; it < 4; it++) {
            const int c = cbase + it * 256;
            float4 a[4], bz[4];
            #pragma unroll
            for (int i = 0; i < 4; i++) a[i] = z1v[(m0 + i) * ROW4 + c];
            #pragma unroll
            for (int j = 0; j < 4; j++) bz[j] = z2v[(n0 + j) * ROW4 + c];
            #pragma unroll
            for (int i = 0; i < 4; i++) {
                #pragma unroll
                for (int j = 0; j < 4; j++) {
                    float dx = a[i].x - bz[j].x, dy = a[i].y - bz[j].y;
                    float dz = a[i].z - bz[j].z, dw = a[i].w - bz[j].w;
                    acc[i * 4 + j] += dx * dx + dy * dy + dz * dz + dw * dw;
                }
            }
        }

        __shared__ float wsum[4][16];
        #pragma unroll
        for (int p = 0; p < 16; p++) {
            float v = acc[p];
            #pragma unroll
            for (int off = 32; off > 0; off >>= 1) v += __shfl_down(v, off, 64);
            if (lane == 0) wsum[wid][p] = v;
        }
        __syncthreads();
        if (t < 16) {
            float s = wsum[0][t] + wsum[1][t] + wsum[2][t] + wsum[3][t];
            int m = m0 + (t >> 2), n = n0 + (t & 3);
            ws[kc * 4096 + m * 64 + n] = s;   // plain store, unique slot
        }
    }
}

// Reduce partials + margins + finalize: one block of 256 threads.
__global__ __launch_bounds__(256) void fused_pass2(const float* __restrict__ ws,
                                                   float* __restrict__ out) {
    const int t = threadIdx.x;
    const int lane = t & 63, wid = t >> 6;

    float msum = 0.f;
    #pragma unroll
    for (int s = 0; s < 6; s++) msum += ws[MSE_OFF + t + s * 256];  // 1536 partials

    float p = 0.f, q = 0.f;
    #pragma unroll
    for (int s = 0; s < 16; s++) {
        int idx = t + s * 256;                                       // 4096 pairs
        float d = (ws[idx] + ws[4096 + idx] + ws[8192 + idx] + ws[12288 + idx])
                  * (1.0f / (float)DIMZ);
        int m = idx >> 6, n = idx & 63;
        if (m == n) { if (d > MARGIN_POS) p += d - MARGIN_POS; }
        else        { if (d < MARGIN_NEG) q += MARGIN_NEG - d; }
    }

    #pragma unroll
    for (int off = 32; off > 0; off >>= 1) {
        msum += __shfl_down(msum, off, 64);
        p    += __shfl_down(p,    off, 64);
        q    += __shfl_down(q,    off, 64);
    }
    __shared__ float sm[4], sp[4], sq[4];
    if (lane == 0) { sm[wid] = msum; sp[wid] = p; sq[wid] = q; }
    __syncthreads();
    if (t == 0) {
        float M = sm[0] + sm[1] + sm[2] + sm[3];
        float P = sp[0] + sp[1] + sp[2] + sp[3];
        float Q = sq[0] + sq[1] + sq[2] + sq[3];
        out[0] = M * (1.0f / (float)N_ELEM)
               + 1.5f * (P / (float)BATCH)
               + 0.5f * (Q / (float)(BATCH * (BATCH - 1)));
    }
}

extern "C" void kernel_launch(void* const* d_in, const int* in_sizes, int n_in,
                              void* d_out, int out_size, void* d_ws, size_t ws_size,
                              hipStream_t stream) {
    const float* outputs1 = (const float*)d_in[0];
    const float* z1       = (const float*)d_in[1];
    const float* outputs2 = (const float*)d_in[2];
    const float* z2       = (const float*)d_in[3];
    const float* input1   = (const float*)d_in[4];
    const float* input2   = (const float*)d_in[5];
    float* out = (float*)d_out;
    float* ws  = (float*)d_ws;

    fused_pass1<<<MSE_BLKS + CB, 256, 0, stream>>>(outputs1, input1, outputs2, input2,
                                                   z1, z2, ws);
    fused_pass2<<<1, 256, 0, stream>>>(ws, out);
}